// Round 4
// baseline (289.070 us; speedup 1.0000x reference)
//
#include <hip/hip_runtime.h>

typedef unsigned long long u64;
typedef unsigned int u32;
typedef unsigned short u16;

#define BATCH 2048
#define DIM   64
#define QSIZE 131072
#define HALFB 1024

#define ROWB   256        // bytes per interleaved [hi|lo] bf16 row (16 chunks of 16B, XOR-swizzled)
#define TILEC  64         // sim-columns (queue rows) per LDS tile
#define TILEB  (TILEC * ROWB)   // 16 KB per buffer
#define NTILE  32         // tiles per block (2048-column slice)

typedef __attribute__((ext_vector_type(8)))  short short8;
typedef __attribute__((ext_vector_type(4)))  short short4v;
typedef __attribute__((ext_vector_type(16))) float f32x16;
typedef __attribute__((ext_vector_type(4)))  float f32x4;

__device__ __forceinline__ u16 bf16rn(float f) {
  u32 b = __float_as_uint(f);
  return (u16)((b + 0x7FFFu + ((b >> 16) & 1u)) >> 16);
}
__device__ __forceinline__ float bf16tof(u16 h) {
  return __uint_as_float(((u32)h) << 16);
}

__device__ __forceinline__ void gload_lds16(const void* g, void* l) {
  __builtin_amdgcn_global_load_lds(
      (__attribute__((address_space(1))) void*)(g),
      (__attribute__((address_space(3))) void*)(l),
      16, 0, 0);
}

// fp32 queue -> interleaved bf16 hi|lo rows (256 B pitch), XOR-swizzled:
// logical 16B-chunk c of row r lands at phys = c ^ (r & 15). The sim kernel
// stages rows LINEARLY via global_load_lds (swizzle preserved) and applies the
// XOR on its ds_read addresses -> reads spread across all 32 LDS banks.
// XCD-aligned producer (block p -> data owned by XCD p&7) + nt loads keep qc
// warm in the local L2. Also zeroes the 2048 argmax slots.
__global__ void preconv_kernel(const float* __restrict__ q, char* __restrict__ qc,
                               u64* __restrict__ ws)
{
  int p = blockIdx.x;
  int b = ((p & 7) << 10) | (p >> 3);       // bijective for 8192 blocks
  int i = b * 256 + threadIdx.x;            // float4 id, QSIZE*16 total
  if (i < BATCH) ws[i] = 0;
  int row = i >> 4;
  int c4  = i & 15;
  f32x4 v = __builtin_nontemporal_load(((const f32x4*)q) + i);
  short4v hv, lv;
#pragma unroll
  for (int k = 0; k < 4; ++k) {
    u16 hb = bf16rn(v[k]);
    u16 lb = bf16rn(v[k] - bf16tof(hb));
    hv[k] = (short)hb;
    lv[k] = (short)lb;
  }
  int chunk = c4 >> 1, half = c4 & 1;
  int ph    = chunk ^ (row & 15);           // hi chunk (logical 0..7)
  int pl    = ph ^ 8;                       // lo chunk (logical 8..15)
  size_t base = (size_t)row * ROWB;
  *(short4v*)(qc + base + ph * 16 + half * 8) = hv;
  *(short4v*)(qc + base + pl * 16 + half * 8) = lv;
}

// sim = x . q^T via 3-pass bf16 hi/lo MFMA, fused row-argmax.
// 2-phase pipelined LDS staging; 16 KB tiles (TILEC=64) keep total LDS at
// 32 KB so 3 blocks/CU are resident (launch_bounds(256,3)). Independent
// blocks decorrelate MFMA vs argmax-VALU phases across waves on each SIMD;
// setprio(1) biases the scheduler toward MFMA-issuing waves (T5 regime).
__global__ __launch_bounds__(256, 3) void sim_argmax_kernel(
    const float* __restrict__ x, const char* __restrict__ qc,
    u64* __restrict__ ws)
{
  __shared__ char smem[2 * TILEB];   // 32 KB double buffer; epilogue table aliases

  const int tid  = threadIdx.x;
  const int lane = tid & 63;
  const int wave = tid >> 6;
  const int wm   = wave & 1;    // m-half (64 rows)
  const int wn   = wave >> 1;   // col-half (32 of 64 cols)
  const int l31  = lane & 31;
  const int lh   = lane >> 5;

  // XCD swizzle: hw linear id -> xcd = hw&7; each XCD owns 8 column groups,
  // all 16 m-blocks of a group stay on that XCD's L2. Bijective for 1024 wgs.
  const int hw   = blockIdx.x + (blockIdx.y << 4);
  const int mx   = (hw >> 3) & 15;
  const int ycol = ((hw & 7) << 3) | (hw >> 7);
  const int mblk = mx * 128;
  const int colbase = ycol * 2048;            // 2048-row queue slice

  const char* qbase = qc + (size_t)colbase * ROWB;

  // ---- prologue: stage tile 0 into buf0 (overlaps A-fragment build) ----
  {
    const char* src = qbase + wave * 4096 + lane * 16;
    char* dst = smem + wave * 4096;
#pragma unroll
    for (int p = 0; p < 4; ++p) gload_lds16(src + p * 1024, dst + p * 1024);
  }

  // persistent A fragments: A[m = l31][k = kt*16 + lh*8 + j]
  short8 ah[2][4], al[2][4];
#pragma unroll
  for (int ms = 0; ms < 2; ++ms) {
    const float* xr = x + (size_t)(mblk + wm * 64 + ms * 32 + l31) * DIM;
#pragma unroll
    for (int kt = 0; kt < 4; ++kt) {
      const float* p = xr + kt * 16 + lh * 8;
      float4 v0 = *(const float4*)(p);
      float4 v1 = *(const float4*)(p + 4);
      float vv[8] = {v0.x, v0.y, v0.z, v0.w, v1.x, v1.y, v1.z, v1.w};
      short8 h, l;
#pragma unroll
      for (int i = 0; i < 8; ++i) {
        u16 hb = bf16rn(vv[i]);
        u16 lb = bf16rn(vv[i] - bf16tof(hb));
        h[i] = (short)hb;
        l[i] = (short)lb;
      }
      ah[ms][kt] = h;
      al[ms][kt] = l;
    }
  }

  float best[2][16];
  u32   bidx[2][16];
#pragma unroll
  for (int ms = 0; ms < 2; ++ms)
#pragma unroll
    for (int r = 0; r < 16; ++r) { best[ms][r] = -3.0e38f; bidx[ms][r] = 0; }

  __syncthreads();   // drains vmcnt(0): tile 0 staged

#pragma unroll 1
  for (int t = 0; t < NTILE; ++t) {
    const char* cur = smem + (t & 1) * TILEB;

    // stage next tile first (T3: issue STAGE before ds_read+MFMA)
    if (t < NTILE - 1) {
      const char* src = qbase + (size_t)(t + 1) * TILEB + wave * 4096 + lane * 16;
      char* dst = smem + ((t + 1) & 1) * TILEB + wave * 4096;
#pragma unroll
      for (int p = 0; p < 4; ++p) gload_lds16(src + p * 1024, dst + p * 1024);
    }

    const int brow = wn * 32 + l31;             // tile-local sim-column
    const int sw   = brow & 15;                 // == global row & 15 (64|16)
    short8 bh[4], bl[4];
#pragma unroll
    for (int kt = 0; kt < 4; ++kt) {
      int ph = (kt * 2 + lh) ^ sw;              // hi chunk, swizzled
      bh[kt] = *(const short8*)(cur + brow * ROWB + (ph << 4));
      bl[kt] = *(const short8*)(cur + brow * ROWB + ((ph ^ 8) << 4));
    }
    const u32 col = (u32)(colbase + t * TILEC + brow);

    // identical accumulation order to the verified kernel: per kt, hh, lh, hl.
#pragma unroll
    for (int ms = 0; ms < 2; ++ms) {
      f32x16 acc;
#pragma unroll
      for (int r = 0; r < 16; ++r) acc[r] = 0.0f;
      __builtin_amdgcn_s_setprio(1);
#pragma unroll
      for (int kt = 0; kt < 4; ++kt) {
        acc = __builtin_amdgcn_mfma_f32_32x32x16_bf16(ah[ms][kt], bh[kt], acc, 0, 0, 0);
        acc = __builtin_amdgcn_mfma_f32_32x32x16_bf16(al[ms][kt], bh[kt], acc, 0, 0, 0);
        acc = __builtin_amdgcn_mfma_f32_32x32x16_bf16(ah[ms][kt], bl[kt], acc, 0, 0, 0);
      }
      __builtin_amdgcn_s_setprio(0);
      // col scans ascending (t asc); strict '>' keeps smallest index.
#pragma unroll
      for (int r = 0; r < 16; ++r) {
        if (acc[r] > best[ms][r]) { best[ms][r] = acc[r]; bidx[ms][r] = col; }
      }
    }

    // one barrier per tile: drains vmcnt(0) (next tile staged) and ensures all
    // waves finished reading buf[t&1] before iter t+1 overwrites it.
    __syncthreads();
  }

  // block reduce: table[row 0..127][l31 0..31], two wn phases, 128-thread scan.
  // table (32 KB) aliases the staging buffers (loop's final barrier).
  u64* table = (u64*)smem;
  if (wn == 0) {
#pragma unroll
    for (int ms = 0; ms < 2; ++ms)
#pragma unroll
      for (int r = 0; r < 16; ++r) {
        int row = wm * 64 + ms * 32 + (r & 3) + 8 * (r >> 2) + 4 * lh;
        u32 fb = __float_as_uint(best[ms][r]);
        fb = (fb & 0x80000000u) ? ~fb : (fb | 0x80000000u);
        table[row * 32 + l31] = ((u64)fb << 32) | (u32)(~bidx[ms][r]);
      }
  }
  __syncthreads();
  if (wn == 1) {
#pragma unroll
    for (int ms = 0; ms < 2; ++ms)
#pragma unroll
      for (int r = 0; r < 16; ++r) {
        int row = wm * 64 + ms * 32 + (r & 3) + 8 * (r >> 2) + 4 * lh;
        u32 fb = __float_as_uint(best[ms][r]);
        fb = (fb & 0x80000000u) ? ~fb : (fb | 0x80000000u);
        u64 pk = ((u64)fb << 32) | (u32)(~bidx[ms][r]);
        u64* slot = &table[row * 32 + l31];
        if (pk > *slot) *slot = pk;   // unique writer per slot in this phase
      }
  }
  __syncthreads();
  if (tid < 128) {
    u64 mx64 = 0;
    // rotated scan start per lane: avoids the 32-way stride-256B bank conflict
    for (int j0 = 0; j0 < 32; ++j0) {
      int j = (j0 + tid) & 31;
      u64 v = table[tid * 32 + j];
      mx64 = (v > mx64) ? v : mx64;
    }
    atomicMax(&ws[mblk + tid], mx64);
  }
}

// Fused tail: new_queue copy-with-substitution (blocks 0..8191), nn gather +
// ptr (blocks 8192..8703). Runs after sim; overwrites the qconv scratch region.
__global__ void finish_kernel(const float* __restrict__ x, const float* __restrict__ q,
                              const int* __restrict__ ptr_in, const u64* __restrict__ ws,
                              float* __restrict__ nn, float* __restrict__ newq,
                              float* __restrict__ nptr)
{
  int bid = blockIdx.x;
  if (bid < 8192) {
    int i = bid * 256 + threadIdx.x;   // float4 index
    int r = i >> 4;
    int c = i & 15;
    int ptr = *ptr_in;
    u32 off = (u32)(r - ptr) & (QSIZE - 1);
    if (off < HALFB) {
      f32x4 v = __builtin_nontemporal_load(((const f32x4*)x) + (off * 16 + c));
      __builtin_nontemporal_store(v, ((f32x4*)newq) + i);
    } else {
      f32x4 v = __builtin_nontemporal_load(((const f32x4*)q) + i);
      __builtin_nontemporal_store(v, ((f32x4*)newq) + i);
    }
  } else {
    int t = (bid - 8192) * 256 + threadIdx.x;  // 0 .. BATCH*DIM-1
    int b = t >> 6;
    int d = t & 63;
    u32 qidx = ~(u32)(ws[b]);
    nn[t] = q[(size_t)qidx * DIM + d];
    if (t == 0) *nptr = (float)(((*ptr_in) + HALFB) & (QSIZE - 1));
  }
}

extern "C" void kernel_launch(void* const* d_in, const int* in_sizes, int n_in,
                              void* d_out, int out_size, void* d_ws, size_t ws_size,
                              hipStream_t stream)
{
  const float* x   = (const float*)d_in[0];
  const float* qx  = (const float*)d_in[1];
  const int*   ptr = (const int*)d_in[2];

  float* out  = (float*)d_out;
  float* nn   = out;
  float* newq = out + BATCH * DIM;
  float* nptr = out + BATCH * DIM + (size_t)QSIZE * DIM;

  char* qc = (char*)newq;   // 32 MB bf16 scratch inside the newq slot
  u64*  ws = (u64*)d_ws;    // 2048 packed (sim, ~idx) slots

  preconv_kernel<<<QSIZE * 16 / 256, 256, 0, stream>>>(qx, qc, ws);

  dim3 grid(BATCH / 128, 64);
  sim_argmax_kernel<<<grid, 256, 0, stream>>>(x, qc, ws);

  finish_kernel<<<8192 + (BATCH * DIM) / 256, 256, 0, stream>>>(
      x, qx, ptr, ws, nn, newq, nptr);
}

// Round 5
// 218.765 us; speedup vs baseline: 1.3214x; 1.3214x over previous
//
#include <hip/hip_runtime.h>

typedef unsigned long long u64;
typedef unsigned int u32;
typedef unsigned short u16;

#define BATCH 2048
#define DIM   64
#define QSIZE 131072
#define HALFB 1024

#define ROWB   256        // bytes per interleaved [hi|lo] bf16 row (16 chunks of 16B, XOR-swizzled)
#define TILEC  64         // sim-columns (queue rows) per LDS tile
#define TILEB  (TILEC * ROWB)   // 16 KB per buffer
#define NTILE  32         // tiles per block (2048-column slice)

typedef __attribute__((ext_vector_type(8)))  short short8;
typedef __attribute__((ext_vector_type(4)))  short short4v;
typedef __attribute__((ext_vector_type(16))) float f32x16;
typedef __attribute__((ext_vector_type(4)))  float f32x4;

__device__ __forceinline__ u16 bf16rn(float f) {
  u32 b = __float_as_uint(f);
  return (u16)((b + 0x7FFFu + ((b >> 16) & 1u)) >> 16);
}
__device__ __forceinline__ float bf16tof(u16 h) {
  return __uint_as_float(((u32)h) << 16);
}

__device__ __forceinline__ void gload_lds16(const void* g, void* l) {
  __builtin_amdgcn_global_load_lds(
      (__attribute__((address_space(1))) void*)(g),
      (__attribute__((address_space(3))) void*)(l),
      16, 0, 0);
}

// fp32 queue -> interleaved bf16 hi|lo rows (256 B pitch), XOR-swizzled:
// logical 16B-chunk c of row r lands at phys = c ^ (r & 15). The sim kernel
// stages rows LINEARLY via global_load_lds (swizzle preserved) and applies the
// XOR on its ds_read addresses -> reads spread across all 32 LDS banks.
// XCD-aligned producer (block p -> data owned by XCD p&7) + nt loads keep qc
// warm in the local L2. Also zeroes the 2048 argmax slots.
__global__ void preconv_kernel(const float* __restrict__ q, char* __restrict__ qc,
                               u64* __restrict__ ws)
{
  int p = blockIdx.x;
  int b = ((p & 7) << 10) | (p >> 3);       // bijective for 8192 blocks
  int i = b * 256 + threadIdx.x;            // float4 id, QSIZE*16 total
  if (i < BATCH) ws[i] = 0;
  int row = i >> 4;
  int c4  = i & 15;
  f32x4 v = __builtin_nontemporal_load(((const f32x4*)q) + i);
  short4v hv, lv;
#pragma unroll
  for (int k = 0; k < 4; ++k) {
    u16 hb = bf16rn(v[k]);
    u16 lb = bf16rn(v[k] - bf16tof(hb));
    hv[k] = (short)hb;
    lv[k] = (short)lb;
  }
  int chunk = c4 >> 1, half = c4 & 1;
  int ph    = chunk ^ (row & 15);           // hi chunk (logical 0..7)
  int pl    = ph ^ 8;                       // lo chunk (logical 8..15)
  size_t base = (size_t)row * ROWB;
  *(short4v*)(qc + base + ph * 16 + half * 8) = hv;
  *(short4v*)(qc + base + pl * 16 + half * 8) = lv;
}

// sim = x . q^T via 3-pass bf16 hi/lo MFMA, fused row-argmax.
// 2-phase pipelined LDS staging; 16 KB tiles, 32 KB LDS total.
// launch_bounds(256,3): 3 blocks/CU (3 waves/SIMD from INDEPENDENT blocks)
// decorrelates MFMA vs argmax-VALU phases. Register diet to fit 512/3=170:
// per-lane argmax column differs only in the 5-bit tile index t, so the
// index state is 8 byte-packed VGPRs (tpack) instead of 32 u32s (bidx).
__global__ __launch_bounds__(256, 3) void sim_argmax_kernel(
    const float* __restrict__ x, const char* __restrict__ qc,
    u64* __restrict__ ws)
{
  __shared__ char smem[2 * TILEB];   // 32 KB double buffer; epilogue table aliases

  const int tid  = threadIdx.x;
  const int lane = tid & 63;
  const int wave = tid >> 6;
  const int wm   = wave & 1;    // m-half (64 rows)
  const int wn   = wave >> 1;   // col-half (32 of 64 cols)
  const int l31  = lane & 31;
  const int lh   = lane >> 5;

  // XCD swizzle: hw linear id -> xcd = hw&7; each XCD owns 8 column groups,
  // all 16 m-blocks of a group stay on that XCD's L2. Bijective for 1024 wgs.
  const int hw   = blockIdx.x + (blockIdx.y << 4);
  const int mx   = (hw >> 3) & 15;
  const int ycol = ((hw & 7) << 3) | (hw >> 7);
  const int mblk = mx * 128;
  const int colbase = ycol * 2048;            // 2048-row queue slice

  const char* qbase = qc + (size_t)colbase * ROWB;

  // ---- prologue: stage tile 0 into buf0 (overlaps A-fragment build) ----
  {
    const char* src = qbase + wave * 4096 + lane * 16;
    char* dst = smem + wave * 4096;
#pragma unroll
    for (int p = 0; p < 4; ++p) gload_lds16(src + p * 1024, dst + p * 1024);
  }

  // persistent A fragments: A[m = l31][k = kt*16 + lh*8 + j]
  short8 ah[2][4], al[2][4];
#pragma unroll
  for (int ms = 0; ms < 2; ++ms) {
    const float* xr = x + (size_t)(mblk + wm * 64 + ms * 32 + l31) * DIM;
#pragma unroll
    for (int kt = 0; kt < 4; ++kt) {
      const float* p = xr + kt * 16 + lh * 8;
      float4 v0 = *(const float4*)(p);
      float4 v1 = *(const float4*)(p + 4);
      float vv[8] = {v0.x, v0.y, v0.z, v0.w, v1.x, v1.y, v1.z, v1.w};
      short8 h, l;
#pragma unroll
      for (int i = 0; i < 8; ++i) {
        u16 hb = bf16rn(vv[i]);
        u16 lb = bf16rn(vv[i] - bf16tof(hb));
        h[i] = (short)hb;
        l[i] = (short)lb;
      }
      ah[ms][kt] = h;
      al[ms][kt] = l;
    }
  }

  float best[2][16];
  u32   tpack[2][4];   // byte-packed winning tile index per [ms][r]
#pragma unroll
  for (int ms = 0; ms < 2; ++ms) {
#pragma unroll
    for (int r = 0; r < 16; ++r) best[ms][r] = -3.0e38f;
#pragma unroll
    for (int r = 0; r < 4; ++r) tpack[ms][r] = 0;
  }

  __syncthreads();   // drains vmcnt(0): tile 0 staged

#pragma unroll 1
  for (int t = 0; t < NTILE; ++t) {
    const char* cur = smem + (t & 1) * TILEB;

    // stage next tile first (T3: issue STAGE before ds_read+MFMA)
    if (t < NTILE - 1) {
      const char* src = qbase + (size_t)(t + 1) * TILEB + wave * 4096 + lane * 16;
      char* dst = smem + ((t + 1) & 1) * TILEB + wave * 4096;
#pragma unroll
      for (int p = 0; p < 4; ++p) gload_lds16(src + p * 1024, dst + p * 1024);
    }

    const int brow = wn * 32 + l31;             // tile-local sim-column
    const int sw   = brow & 15;                 // == global row & 15 (64|16)
    short8 bh[4], bl[4];
#pragma unroll
    for (int kt = 0; kt < 4; ++kt) {
      int ph = (kt * 2 + lh) ^ sw;              // hi chunk, swizzled
      bh[kt] = *(const short8*)(cur + brow * ROWB + (ph << 4));
      bl[kt] = *(const short8*)(cur + brow * ROWB + ((ph ^ 8) << 4));
    }

    // identical accumulation order to the verified kernel: per kt, hh, lh, hl.
#pragma unroll
    for (int ms = 0; ms < 2; ++ms) {
      f32x16 acc;
#pragma unroll
      for (int r = 0; r < 16; ++r) acc[r] = 0.0f;
      __builtin_amdgcn_s_setprio(1);
#pragma unroll
      for (int kt = 0; kt < 4; ++kt) {
        acc = __builtin_amdgcn_mfma_f32_32x32x16_bf16(ah[ms][kt], bh[kt], acc, 0, 0, 0);
        acc = __builtin_amdgcn_mfma_f32_32x32x16_bf16(al[ms][kt], bh[kt], acc, 0, 0, 0);
        acc = __builtin_amdgcn_mfma_f32_32x32x16_bf16(ah[ms][kt], bl[kt], acc, 0, 0, 0);
      }
      __builtin_amdgcn_s_setprio(0);
      // t scans ascending; strict '>' keeps smallest tile index.
#pragma unroll
      for (int r = 0; r < 16; ++r) {
        u32 tp  = tpack[ms][r >> 2];
        u32 sh  = (u32)((r & 3) * 8);
        u32 ins = (tp & ~(0xFFu << sh)) | ((u32)t << sh);
        bool c  = acc[r] > best[ms][r];
        best[ms][r]     = c ? acc[r] : best[ms][r];
        tpack[ms][r >> 2] = c ? ins : tp;
      }
    }

    // one barrier per tile: drains vmcnt(0) (next tile staged) and ensures all
    // waves finished reading buf[t&1] before iter t+1 overwrites it.
    __syncthreads();
  }

  // block reduce: table[row 0..127][l31 0..31], two wn phases, 128-thread scan.
  // table (32 KB) aliases the staging buffers (loop's final barrier).
  // column reconstruction: col = colbase + t*64 + wn*32 + l31.
  u64* table = (u64*)smem;
  if (wn == 0) {
#pragma unroll
    for (int ms = 0; ms < 2; ++ms)
#pragma unroll
      for (int r = 0; r < 16; ++r) {
        int row = wm * 64 + ms * 32 + (r & 3) + 8 * (r >> 2) + 4 * lh;
        u32 tb = (tpack[ms][r >> 2] >> ((r & 3) * 8)) & 0xFFu;
        u32 colr = (u32)(colbase + (int)tb * TILEC + wn * 32 + l31);
        u32 fb = __float_as_uint(best[ms][r]);
        fb = (fb & 0x80000000u) ? ~fb : (fb | 0x80000000u);
        table[row * 32 + l31] = ((u64)fb << 32) | (u32)(~colr);
      }
  }
  __syncthreads();
  if (wn == 1) {
#pragma unroll
    for (int ms = 0; ms < 2; ++ms)
#pragma unroll
      for (int r = 0; r < 16; ++r) {
        int row = wm * 64 + ms * 32 + (r & 3) + 8 * (r >> 2) + 4 * lh;
        u32 tb = (tpack[ms][r >> 2] >> ((r & 3) * 8)) & 0xFFu;
        u32 colr = (u32)(colbase + (int)tb * TILEC + wn * 32 + l31);
        u32 fb = __float_as_uint(best[ms][r]);
        fb = (fb & 0x80000000u) ? ~fb : (fb | 0x80000000u);
        u64 pk = ((u64)fb << 32) | (u32)(~colr);
        u64* slot = &table[row * 32 + l31];
        if (pk > *slot) *slot = pk;   // unique writer per slot in this phase
      }
  }
  __syncthreads();
  if (tid < 128) {
    u64 mx64 = 0;
    // rotated scan start per lane: avoids the 32-way stride-256B bank conflict
    for (int j0 = 0; j0 < 32; ++j0) {
      int j = (j0 + tid) & 31;
      u64 v = table[tid * 32 + j];
      mx64 = (v > mx64) ? v : mx64;
    }
    atomicMax(&ws[mblk + tid], mx64);
  }
}

// Fused tail: new_queue copy-with-substitution (blocks 0..8191), nn gather +
// ptr (blocks 8192..8703). Runs after sim; overwrites the qconv scratch region.
__global__ void finish_kernel(const float* __restrict__ x, const float* __restrict__ q,
                              const int* __restrict__ ptr_in, const u64* __restrict__ ws,
                              float* __restrict__ nn, float* __restrict__ newq,
                              float* __restrict__ nptr)
{
  int bid = blockIdx.x;
  if (bid < 8192) {
    int i = bid * 256 + threadIdx.x;   // float4 index
    int r = i >> 4;
    int c = i & 15;
    int ptr = *ptr_in;
    u32 off = (u32)(r - ptr) & (QSIZE - 1);
    if (off < HALFB) {
      f32x4 v = __builtin_nontemporal_load(((const f32x4*)x) + (off * 16 + c));
      __builtin_nontemporal_store(v, ((f32x4*)newq) + i);
    } else {
      f32x4 v = __builtin_nontemporal_load(((const f32x4*)q) + i);
      __builtin_nontemporal_store(v, ((f32x4*)newq) + i);
    }
  } else {
    int t = (bid - 8192) * 256 + threadIdx.x;  // 0 .. BATCH*DIM-1
    int b = t >> 6;
    int d = t & 63;
    u32 qidx = ~(u32)(ws[b]);
    nn[t] = q[(size_t)qidx * DIM + d];
    if (t == 0) *nptr = (float)(((*ptr_in) + HALFB) & (QSIZE - 1));
  }
}

extern "C" void kernel_launch(void* const* d_in, const int* in_sizes, int n_in,
                              void* d_out, int out_size, void* d_ws, size_t ws_size,
                              hipStream_t stream)
{
  const float* x   = (const float*)d_in[0];
  const float* qx  = (const float*)d_in[1];
  const int*   ptr = (const int*)d_in[2];

  float* out  = (float*)d_out;
  float* nn   = out;
  float* newq = out + BATCH * DIM;
  float* nptr = out + BATCH * DIM + (size_t)QSIZE * DIM;

  char* qc = (char*)newq;   // 32 MB bf16 scratch inside the newq slot
  u64*  ws = (u64*)d_ws;    // 2048 packed (sim, ~idx) slots

  preconv_kernel<<<QSIZE * 16 / 256, 256, 0, stream>>>(qx, qc, ws);

  dim3 grid(BATCH / 128, 64);
  sim_argmax_kernel<<<grid, 256, 0, stream>>>(x, qc, ws);

  finish_kernel<<<8192 + (BATCH * DIM) / 256, 256, 0, stream>>>(
      x, qx, ptr, ws, nn, newq, nptr);
}

// Round 6
// 210.806 us; speedup vs baseline: 1.3713x; 1.0378x over previous
//
#include <hip/hip_runtime.h>

typedef unsigned long long u64;
typedef unsigned int u32;
typedef unsigned short u16;

#define BATCH 2048
#define DIM   64
#define QSIZE 131072
#define HALFB 1024

// qc layout: 4096 blocks of 32 queue rows. Each 8 KB block:
//   hi plane [chunk c=0..7][row r&31][16B]  at  b*8192 + c*512 + (r&31)*16
//   lo plane same + 4096
// chunk c holds elements k = c*8 .. c*8+7 of the row (bf16, 2B each).
// A wave's MFMA B-fragment load (lane = lh*32+l31 reads row l31, chunk kt*2+lh)
// is then base + kt*1024 + lane*16 -> one fully coalesced 1KB dwordx4.
#define BLKB 8192

typedef __attribute__((ext_vector_type(8)))  short short8;
typedef __attribute__((ext_vector_type(16))) float f32x16;
typedef __attribute__((ext_vector_type(4)))  float f32x4;

__device__ __forceinline__ u16 bf16rn(float f) {
  u32 b = __float_as_uint(f);
  return (u16)((b + 0x7FFFu + ((b >> 16) & 1u)) >> 16);
}
__device__ __forceinline__ float bf16tof(u16 h) {
  return __uint_as_float(((u32)h) << 16);
}

// fp32 queue -> bf16 hi/lo in MFMA-fragment order (see layout above).
// Block p handles exactly one 8KB qc block b; remap b = ((p&7)<<9)|(p>>3) so
// XCD p&7 (round-robin dispatch) writes the contiguous 4MB qc range that sim
// blocks on the SAME XCD read -> producer-consumer L2 locality.
// Reads: tid-consecutive 32B -> perfectly coalesced. Also zeroes argmax slots.
__global__ void preconv_kernel(const float* __restrict__ q, char* __restrict__ qc,
                               u64* __restrict__ ws)
{
  int raw = blockIdx.x * 256 + threadIdx.x;
  if (raw < BATCH) ws[raw] = 0;
  int p = blockIdx.x;                  // 4096 blocks
  int b = ((p & 7) << 9) | (p >> 3);   // bijective for 4096
  int tid = threadIdx.x;
  int r5 = tid >> 3;                   // row in block 0..31
  int c  = tid & 7;                    // chunk 0..7
  const float* src = q + (size_t)(b * 32 + r5) * DIM + c * 8;
  f32x4 v0 = __builtin_nontemporal_load((const f32x4*)src);
  f32x4 v1 = __builtin_nontemporal_load((const f32x4*)(src + 4));
  float vv[8] = {v0[0], v0[1], v0[2], v0[3], v1[0], v1[1], v1[2], v1[3]};
  short8 h, l;
#pragma unroll
  for (int j = 0; j < 8; ++j) {
    u16 hb = bf16rn(vv[j]);
    u16 lb = bf16rn(vv[j] - bf16tof(hb));
    h[j] = (short)hb;
    l[j] = (short)lb;
  }
  char* dst = qc + (size_t)b * BLKB + c * 512 + r5 * 16;
  *(short8*)(dst)        = h;
  *(short8*)(dst + 4096) = l;
}

// sim = x . q^T via 3-pass bf16 hi/lo MFMA, fused row-argmax.
// Barrier-free, LDS-free main loop: B fragments stream global->VGPR via fully
// coalesced 1KB loads from the fragment-ordered qc (L2-resident, XCD-pinned),
// double-buffered with static names. No __syncthreads until the epilogue ->
// waves free-run, so one wave's argmax-VALU burst overlaps the other's MFMA
// chains on the same SIMD. MFMA operand values/order identical to the
// verified staged kernel.
__global__ __launch_bounds__(256, 2) void sim_argmax_kernel(
    const float* __restrict__ x, const char* __restrict__ qc,
    u64* __restrict__ ws)
{
  __shared__ u64 table[128 * 32];   // 32 KB, epilogue reduce only

  const int tid  = threadIdx.x;
  const int lane = tid & 63;
  const int wave = tid >> 6;
  const int wm   = wave & 1;    // m-half (64 rows)
  const int wn   = wave >> 1;   // col-half (1024 of 2048 cols)
  const int l31  = lane & 31;
  const int lh   = lane >> 5;

  // XCD swizzle: hw linear id -> xcd = hw&7; each XCD owns 8 column groups,
  // all 16 m-blocks of a group stay on that XCD's L2. Bijective for 1024 wgs.
  const int hw   = blockIdx.x + (blockIdx.y << 4);
  const int mx   = (hw >> 3) & 15;
  const int ycol = ((hw & 7) << 3) | (hw >> 7);
  const int mblk = mx * 128;
  const int colbase = ycol * 2048;            // 2048-row queue slice

  // wave's 32 fragment-blocks: colgroup slice + wn half (32 blocks of 32 rows)
  const char* wbase = qc + (size_t)colbase * 256 + (size_t)wn * 32 * BLKB;
  const u32 lane16 = (u32)lane * 16;

  // persistent A fragments: A[m = l31][k = kt*16 + lh*8 + j]
  short8 ah[2][4], al[2][4];
#pragma unroll
  for (int ms = 0; ms < 2; ++ms) {
    const float* xr = x + (size_t)(mblk + wm * 64 + ms * 32 + l31) * DIM;
#pragma unroll
    for (int kt = 0; kt < 4; ++kt) {
      const float* p = xr + kt * 16 + lh * 8;
      float4 v0 = *(const float4*)(p);
      float4 v1 = *(const float4*)(p + 4);
      float vv[8] = {v0.x, v0.y, v0.z, v0.w, v1.x, v1.y, v1.z, v1.w};
      short8 h, l;
#pragma unroll
      for (int i = 0; i < 8; ++i) {
        u16 hb = bf16rn(vv[i]);
        u16 lb = bf16rn(vv[i] - bf16tof(hb));
        h[i] = (short)hb;
        l[i] = (short)lb;
      }
      ah[ms][kt] = h;
      al[ms][kt] = l;
    }
  }

  float best[2][16];
  u32   bidx[2][16];
#pragma unroll
  for (int ms = 0; ms < 2; ++ms)
#pragma unroll
    for (int r = 0; r < 16; ++r) { best[ms][r] = -3.0e38f; bidx[ms][r] = 0; }

  short8 pAh[4], pAl[4], pBh[4], pBl[4];

#define LOADB(BH, BL, T) do {                                     \
    const char* p_ = wbase + (size_t)(T) * BLKB + lane16;         \
    BH[0] = *(const short8*)(p_ +    0);                          \
    BH[1] = *(const short8*)(p_ + 1024);                          \
    BH[2] = *(const short8*)(p_ + 2048);                          \
    BH[3] = *(const short8*)(p_ + 3072);                          \
    BL[0] = *(const short8*)(p_ + 4096);                          \
    BL[1] = *(const short8*)(p_ + 5120);                          \
    BL[2] = *(const short8*)(p_ + 6144);                          \
    BL[3] = *(const short8*)(p_ + 7168);                          \
  } while (0)

  // identical accumulation order to the verified kernel: per kt, hh, lh, hl.
#define COMPUTE(BH, BL, COL) do {                                              \
    const u32 col_ = (COL);                                                    \
    _Pragma("unroll")                                                          \
    for (int ms = 0; ms < 2; ++ms) {                                           \
      f32x16 acc;                                                              \
      _Pragma("unroll")                                                        \
      for (int r = 0; r < 16; ++r) acc[r] = 0.0f;                              \
      __builtin_amdgcn_s_setprio(1);                                           \
      _Pragma("unroll")                                                        \
      for (int kt = 0; kt < 4; ++kt) {                                         \
        acc = __builtin_amdgcn_mfma_f32_32x32x16_bf16(ah[ms][kt], BH[kt], acc, 0, 0, 0); \
        acc = __builtin_amdgcn_mfma_f32_32x32x16_bf16(al[ms][kt], BH[kt], acc, 0, 0, 0); \
        acc = __builtin_amdgcn_mfma_f32_32x32x16_bf16(ah[ms][kt], BL[kt], acc, 0, 0, 0); \
      }                                                                        \
      __builtin_amdgcn_s_setprio(0);                                           \
      /* col ascends per lane (t asc); strict '>' keeps smallest index */      \
      _Pragma("unroll")                                                        \
      for (int r = 0; r < 16; ++r) {                                           \
        if (acc[r] > best[ms][r]) { best[ms][r] = acc[r]; bidx[ms][r] = col_; } \
      }                                                                        \
    }                                                                          \
  } while (0)

  const u32 colw = (u32)(colbase + wn * 1024 + l31);

  LOADB(pAh, pAl, 0);
#pragma unroll 1
  for (int t = 0; t < 32; t += 2) {
    LOADB(pBh, pBl, t + 1);
    COMPUTE(pAh, pAl, colw + (u32)t * 32);
    LOADB(pAh, pAl, (t + 2) & 31);   // wraps to block 0 on last iter (unused)
    COMPUTE(pBh, pBl, colw + (u32)(t + 1) * 32);
  }

#undef LOADB
#undef COMPUTE

  // block reduce: table[row 0..127][l31 0..31], two wn phases, 128-thread scan
  if (wn == 0) {
#pragma unroll
    for (int ms = 0; ms < 2; ++ms)
#pragma unroll
      for (int r = 0; r < 16; ++r) {
        int row = wm * 64 + ms * 32 + (r & 3) + 8 * (r >> 2) + 4 * lh;
        u32 fb = __float_as_uint(best[ms][r]);
        fb = (fb & 0x80000000u) ? ~fb : (fb | 0x80000000u);
        table[row * 32 + l31] = ((u64)fb << 32) | (u32)(~bidx[ms][r]);
      }
  }
  __syncthreads();
  if (wn == 1) {
#pragma unroll
    for (int ms = 0; ms < 2; ++ms)
#pragma unroll
      for (int r = 0; r < 16; ++r) {
        int row = wm * 64 + ms * 32 + (r & 3) + 8 * (r >> 2) + 4 * lh;
        u32 fb = __float_as_uint(best[ms][r]);
        fb = (fb & 0x80000000u) ? ~fb : (fb | 0x80000000u);
        u64 pk = ((u64)fb << 32) | (u32)(~bidx[ms][r]);
        u64* slot = &table[row * 32 + l31];
        if (pk > *slot) *slot = pk;   // unique writer per slot in this phase
      }
  }
  __syncthreads();
  if (tid < 128) {
    u64 mx64 = 0;
    // rotated scan start per lane: avoids the 32-way stride-256B bank conflict
    for (int j0 = 0; j0 < 32; ++j0) {
      int j = (j0 + tid) & 31;
      u64 v = table[tid * 32 + j];
      mx64 = (v > mx64) ? v : mx64;
    }
    atomicMax(&ws[mblk + tid], mx64);
  }
}

// Fused tail: new_queue copy-with-substitution (blocks 0..8191), nn gather +
// ptr (blocks 8192..8703). Runs after sim; overwrites the qconv scratch region.
__global__ void finish_kernel(const float* __restrict__ x, const float* __restrict__ q,
                              const int* __restrict__ ptr_in, const u64* __restrict__ ws,
                              float* __restrict__ nn, float* __restrict__ newq,
                              float* __restrict__ nptr)
{
  int bid = blockIdx.x;
  if (bid < 8192) {
    int i = bid * 256 + threadIdx.x;   // float4 index
    int r = i >> 4;
    int c = i & 15;
    int ptr = *ptr_in;
    u32 off = (u32)(r - ptr) & (QSIZE - 1);
    if (off < HALFB) {
      f32x4 v = __builtin_nontemporal_load(((const f32x4*)x) + (off * 16 + c));
      __builtin_nontemporal_store(v, ((f32x4*)newq) + i);
    } else {
      f32x4 v = __builtin_nontemporal_load(((const f32x4*)q) + i);
      __builtin_nontemporal_store(v, ((f32x4*)newq) + i);
    }
  } else {
    int t = (bid - 8192) * 256 + threadIdx.x;  // 0 .. BATCH*DIM-1
    int b = t >> 6;
    int d = t & 63;
    u32 qidx = ~(u32)(ws[b]);
    nn[t] = q[(size_t)qidx * DIM + d];
    if (t == 0) *nptr = (float)(((*ptr_in) + HALFB) & (QSIZE - 1));
  }
}

extern "C" void kernel_launch(void* const* d_in, const int* in_sizes, int n_in,
                              void* d_out, int out_size, void* d_ws, size_t ws_size,
                              hipStream_t stream)
{
  const float* x   = (const float*)d_in[0];
  const float* qx  = (const float*)d_in[1];
  const int*   ptr = (const int*)d_in[2];

  float* out  = (float*)d_out;
  float* nn   = out;
  float* newq = out + BATCH * DIM;
  float* nptr = out + BATCH * DIM + (size_t)QSIZE * DIM;

  char* qc = (char*)newq;   // 32 MB bf16 scratch inside the newq slot
  u64*  ws = (u64*)d_ws;    // 2048 packed (sim, ~idx) slots

  preconv_kernel<<<QSIZE / 32, 256, 0, stream>>>(qx, qc, ws);

  dim3 grid(BATCH / 128, 64);
  sim_argmax_kernel<<<grid, 256, 0, stream>>>(x, qc, ws);

  finish_kernel<<<8192 + (BATCH * DIM) / 256, 256, 0, stream>>>(
      x, qx, ptr, ws, nn, newq, nptr);
}

// Round 7
// 203.972 us; speedup vs baseline: 1.4172x; 1.0335x over previous
//
#include <hip/hip_runtime.h>

typedef unsigned long long u64;
typedef unsigned int u32;
typedef unsigned short u16;

#define BATCH 2048
#define DIM   64
#define QSIZE 131072
#define HALFB 1024

// qc layout: 4096 blocks of 32 queue rows. Each 8 KB block:
//   hi plane [chunk c=0..7][row r&31][16B]  at  b*8192 + c*512 + (r&31)*16
//   lo plane same + 4096
// chunk c holds elements k = c*8 .. c*8+7 of the row (bf16, 2B each).
// A wave's MFMA B-fragment load (lane = lh*32+l31 reads row l31, chunk kt*2+lh)
// is then base + kt*1024 + lane*16 -> one fully coalesced 1KB dwordx4.
#define BLKB 8192

typedef __attribute__((ext_vector_type(8)))  short short8;
typedef __attribute__((ext_vector_type(16))) float f32x16;
typedef __attribute__((ext_vector_type(4)))  float f32x4;

__device__ __forceinline__ u16 bf16rn(float f) {
  u32 b = __float_as_uint(f);
  return (u16)((b + 0x7FFFu + ((b >> 16) & 1u)) >> 16);
}
__device__ __forceinline__ float bf16tof(u16 h) {
  return __uint_as_float(((u32)h) << 16);
}

// fp32 queue -> bf16 hi/lo in MFMA-fragment order (see layout above).
// Block p handles exactly one 8KB qc block b; remap b = ((p&7)<<9)|(p>>3) so
// XCD p&7 (round-robin dispatch) writes the contiguous 4MB qc range that sim
// blocks on the SAME XCD read -> producer-consumer L2 locality.
// Reads: tid-consecutive 32B -> perfectly coalesced. Also zeroes argmax slots.
__global__ void preconv_kernel(const float* __restrict__ q, char* __restrict__ qc,
                               u64* __restrict__ ws)
{
  int raw = blockIdx.x * 256 + threadIdx.x;
  if (raw < BATCH) ws[raw] = 0;
  int p = blockIdx.x;                  // 4096 blocks
  int b = ((p & 7) << 9) | (p >> 3);   // bijective for 4096
  int tid = threadIdx.x;
  int r5 = tid >> 3;                   // row in block 0..31
  int c  = tid & 7;                    // chunk 0..7
  const float* src = q + (size_t)(b * 32 + r5) * DIM + c * 8;
  f32x4 v0 = *(const f32x4*)src;
  f32x4 v1 = *(const f32x4*)(src + 4);
  float vv[8] = {v0[0], v0[1], v0[2], v0[3], v1[0], v1[1], v1[2], v1[3]};
  short8 h, l;
#pragma unroll
  for (int j = 0; j < 8; ++j) {
    u16 hb = bf16rn(vv[j]);
    u16 lb = bf16rn(vv[j] - bf16tof(hb));
    h[j] = (short)hb;
    l[j] = (short)lb;
  }
  char* dst = qc + (size_t)b * BLKB + c * 512 + r5 * 16;
  *(short8*)(dst)        = h;
  *(short8*)(dst + 4096) = l;
}

// sim = x . q^T via 3-pass bf16 hi/lo MFMA, fused row-argmax.
// Barrier-free, LDS-free main loop (R6 structure) + HALF-TILE SOFTWARE
// PIPELINING of the argmax: ARGMAX(acc of the PREVIOUS chain) is issued while
// the current 12-MFMA chain is in flight. This breaks the R0..R6 invariant
// stall (argmax depended on the just-issued dependent MFMA chain -> wave
// waited full chain latency every tile; MfmaUtil pinned at 45%). Chains now
// issue back-to-back into the matrix pipe; argmax VALU fills the bubbles.
__global__ __launch_bounds__(256, 2) void sim_argmax_kernel(
    const float* __restrict__ x, const char* __restrict__ qc,
    u64* __restrict__ ws)
{
  __shared__ u64 table[128 * 32];   // 32 KB, epilogue reduce only

  const int tid  = threadIdx.x;
  const int lane = tid & 63;
  const int wave = tid >> 6;
  const int wm   = wave & 1;    // m-half (64 rows)
  const int wn   = wave >> 1;   // col-half (1024 of 2048 cols)
  const int l31  = lane & 31;
  const int lh   = lane >> 5;

  // XCD swizzle: hw linear id -> xcd = hw&7; each XCD owns 8 column groups,
  // all 16 m-blocks of a group stay on that XCD's L2. Bijective for 1024 wgs.
  const int hw   = blockIdx.x + (blockIdx.y << 4);
  const int mx   = (hw >> 3) & 15;
  const int ycol = ((hw & 7) << 3) | (hw >> 7);
  const int mblk = mx * 128;
  const int colbase = ycol * 2048;            // 2048-row queue slice

  // wave's 32 fragment-blocks: colgroup slice + wn half (32 blocks of 32 rows)
  const char* wbase = qc + (size_t)colbase * 256 + (size_t)wn * 32 * BLKB;
  const u32 lane16 = (u32)lane * 16;

  // persistent A fragments: A[m = l31][k = kt*16 + lh*8 + j]
  short8 ah[2][4], al[2][4];
#pragma unroll
  for (int ms = 0; ms < 2; ++ms) {
    const float* xr = x + (size_t)(mblk + wm * 64 + ms * 32 + l31) * DIM;
#pragma unroll
    for (int kt = 0; kt < 4; ++kt) {
      const float* p = xr + kt * 16 + lh * 8;
      float4 v0 = *(const float4*)(p);
      float4 v1 = *(const float4*)(p + 4);
      float vv[8] = {v0.x, v0.y, v0.z, v0.w, v1.x, v1.y, v1.z, v1.w};
      short8 h, l;
#pragma unroll
      for (int i = 0; i < 8; ++i) {
        u16 hb = bf16rn(vv[i]);
        u16 lb = bf16rn(vv[i] - bf16tof(hb));
        h[i] = (short)hb;
        l[i] = (short)lb;
      }
      ah[ms][kt] = h;
      al[ms][kt] = l;
    }
  }

  float best[2][16];
  u32   bidx[2][16];
#pragma unroll
  for (int ms = 0; ms < 2; ++ms)
#pragma unroll
    for (int r = 0; r < 16; ++r) { best[ms][r] = -3.0e38f; bidx[ms][r] = 0; }

  short8 pAh[4], pAl[4], pBh[4], pBl[4];
  f32x16 accA, accB;

#define LOADB(BH, BL, T) do {                                     \
    const char* p_ = wbase + (size_t)(T) * BLKB + lane16;         \
    BH[0] = *(const short8*)(p_ +    0);                          \
    BH[1] = *(const short8*)(p_ + 1024);                          \
    BH[2] = *(const short8*)(p_ + 2048);                          \
    BH[3] = *(const short8*)(p_ + 3072);                          \
    BL[0] = *(const short8*)(p_ + 4096);                          \
    BL[1] = *(const short8*)(p_ + 5120);                          \
    BL[2] = *(const short8*)(p_ + 6144);                          \
    BL[3] = *(const short8*)(p_ + 7168);                          \
  } while (0)

  // identical accumulation order to the verified kernel: per kt, hh, lh, hl.
#define CHAIN(ACC, BH, BL, MS) do {                                            \
    _Pragma("unroll")                                                          \
    for (int r = 0; r < 16; ++r) ACC[r] = 0.0f;                                \
    __builtin_amdgcn_s_setprio(1);                                             \
    _Pragma("unroll")                                                          \
    for (int kt = 0; kt < 4; ++kt) {                                           \
      ACC = __builtin_amdgcn_mfma_f32_32x32x16_bf16(ah[MS][kt], BH[kt], ACC, 0, 0, 0); \
      ACC = __builtin_amdgcn_mfma_f32_32x32x16_bf16(al[MS][kt], BH[kt], ACC, 0, 0, 0); \
      ACC = __builtin_amdgcn_mfma_f32_32x32x16_bf16(ah[MS][kt], BL[kt], ACC, 0, 0, 0); \
    }                                                                          \
    __builtin_amdgcn_s_setprio(0);                                             \
  } while (0)

  // per-(ms,r,lane) columns scan strictly ascending in t; '>' keeps smallest.
#define ARGMAX(ACC, MS, COL) do {                                              \
    const u32 c_ = (COL);                                                      \
    _Pragma("unroll")                                                          \
    for (int r = 0; r < 16; ++r) {                                             \
      if (ACC[r] > best[MS][r]) { best[MS][r] = ACC[r]; bidx[MS][r] = c_; }    \
    }                                                                          \
  } while (0)

  const u32 colw = (u32)(colbase + wn * 1024 + l31);

  // prologue: tile 0 chains (argmax deferred)
  LOADB(pAh, pAl, 0);
  CHAIN(accA, pAh, pAl, 0);
  LOADB(pBh, pBl, 1);
  CHAIN(accB, pAh, pAl, 1);

  // main: 15 iterations x 2 tiles, argmax offset one chain back
#pragma unroll 1
  for (int t = 1; t < 31; t += 2) {
    LOADB(pAh, pAl, t + 1);
    ARGMAX(accA, 0, colw + (u32)(t - 1) * 32);
    CHAIN(accA, pBh, pBl, 0);
    ARGMAX(accB, 1, colw + (u32)(t - 1) * 32);
    CHAIN(accB, pBh, pBl, 1);
    LOADB(pBh, pBl, t + 2);
    ARGMAX(accA, 0, colw + (u32)t * 32);
    CHAIN(accA, pAh, pAl, 0);
    ARGMAX(accB, 1, colw + (u32)t * 32);
    CHAIN(accB, pAh, pAl, 1);
  }

  // epilogue: tile 31 (in pB), then final argmaxes
  ARGMAX(accA, 0, colw + 30u * 32);
  CHAIN(accA, pBh, pBl, 0);
  ARGMAX(accB, 1, colw + 30u * 32);
  CHAIN(accB, pBh, pBl, 1);
  ARGMAX(accA, 0, colw + 31u * 32);
  ARGMAX(accB, 1, colw + 31u * 32);

#undef LOADB
#undef CHAIN
#undef ARGMAX

  // block reduce: table[row 0..127][l31 0..31], two wn phases, 128-thread scan
  if (wn == 0) {
#pragma unroll
    for (int ms = 0; ms < 2; ++ms)
#pragma unroll
      for (int r = 0; r < 16; ++r) {
        int row = wm * 64 + ms * 32 + (r & 3) + 8 * (r >> 2) + 4 * lh;
        u32 fb = __float_as_uint(best[ms][r]);
        fb = (fb & 0x80000000u) ? ~fb : (fb | 0x80000000u);
        table[row * 32 + l31] = ((u64)fb << 32) | (u32)(~bidx[ms][r]);
      }
  }
  __syncthreads();
  if (wn == 1) {
#pragma unroll
    for (int ms = 0; ms < 2; ++ms)
#pragma unroll
      for (int r = 0; r < 16; ++r) {
        int row = wm * 64 + ms * 32 + (r & 3) + 8 * (r >> 2) + 4 * lh;
        u32 fb = __float_as_uint(best[ms][r]);
        fb = (fb & 0x80000000u) ? ~fb : (fb | 0x80000000u);
        u64 pk = ((u64)fb << 32) | (u32)(~bidx[ms][r]);
        u64* slot = &table[row * 32 + l31];
        if (pk > *slot) *slot = pk;   // unique writer per slot in this phase
      }
  }
  __syncthreads();
  if (tid < 128) {
    u64 mx64 = 0;
    // rotated scan start per lane: avoids the 32-way stride-256B bank conflict
    for (int j0 = 0; j0 < 32; ++j0) {
      int j = (j0 + tid) & 31;
      u64 v = table[tid * 32 + j];
      mx64 = (v > mx64) ? v : mx64;
    }
    atomicMax(&ws[mblk + tid], mx64);
  }
}

// Fused tail: new_queue copy-with-substitution (blocks 0..8191), nn gather +
// ptr (blocks 8192..8703). Plain (cached) loads/stores: the nontemporal
// variants measured ~15 us slower across rounds (q/newq benefit from L2/L3).
__global__ void finish_kernel(const float* __restrict__ x, const float* __restrict__ q,
                              const int* __restrict__ ptr_in, const u64* __restrict__ ws,
                              float* __restrict__ nn, float* __restrict__ newq,
                              float* __restrict__ nptr)
{
  int bid = blockIdx.x;
  if (bid < 8192) {
    int i = bid * 256 + threadIdx.x;   // float4 index
    int r = i >> 4;
    int c = i & 15;
    int ptr = *ptr_in;
    u32 off = (u32)(r - ptr) & (QSIZE - 1);
    float4 v = (off < HALFB) ? ((const float4*)x)[off * 16 + c]
                             : ((const float4*)q)[i];
    ((float4*)newq)[i] = v;
  } else {
    int t = (bid - 8192) * 256 + threadIdx.x;  // 0 .. BATCH*DIM-1
    int b = t >> 6;
    int d = t & 63;
    u32 qidx = ~(u32)(ws[b]);
    nn[t] = q[(size_t)qidx * DIM + d];
    if (t == 0) *nptr = (float)(((*ptr_in) + HALFB) & (QSIZE - 1));
  }
}

extern "C" void kernel_launch(void* const* d_in, const int* in_sizes, int n_in,
                              void* d_out, int out_size, void* d_ws, size_t ws_size,
                              hipStream_t stream)
{
  const float* x   = (const float*)d_in[0];
  const float* qx  = (const float*)d_in[1];
  const int*   ptr = (const int*)d_in[2];

  float* out  = (float*)d_out;
  float* nn   = out;
  float* newq = out + BATCH * DIM;
  float* nptr = out + BATCH * DIM + (size_t)QSIZE * DIM;

  char* qc = (char*)newq;   // 32 MB bf16 scratch inside the newq slot
  u64*  ws = (u64*)d_ws;    // 2048 packed (sim, ~idx) slots

  preconv_kernel<<<QSIZE / 32, 256, 0, stream>>>(qx, qc, ws);

  dim3 grid(BATCH / 128, 64);
  sim_argmax_kernel<<<grid, 256, 0, stream>>>(x, qc, ws);

  finish_kernel<<<8192 + (BATCH * DIM) / 256, 256, 0, stream>>>(
      x, qx, ptr, ws, nn, newq, nptr);
}